// Round 19
// baseline (248.417 us; speedup 1.0000x reference)
//
#include <hip/hip_runtime.h>

#define D     384
#define E     769      // 1 + 2*D
#define NTOK  4096
#define BPN   32       // B*P
#define NCH   64       // chunks of 64 rows per (b,p)

typedef short s16x8 __attribute__((ext_vector_type(8)));
typedef float f32x4 __attribute__((ext_vector_type(4)));
typedef float f32x2 __attribute__((ext_vector_type(2)));

__device__ __forceinline__ unsigned short f2bf(float f){
  unsigned int u = __builtin_bit_cast(unsigned int, f);
  u += 0x7FFFu + ((u >> 16) & 1u);          // round-to-nearest-even
  return (unsigned short)(u >> 16);
}

// ---------------- K0: pack wq; build FRAGMENT-ORDERED bf16 weights ----------------
__global__ void k0_prep(const float* __restrict__ wqkv, const float* __restrict__ wout,
                        float* __restrict__ wq, unsigned short* __restrict__ wvF,
                        unsigned short* __restrict__ woF){
  int tid = blockIdx.x*256 + threadIdx.x;     // 0 .. 147455
  if (tid < D) wq[tid] = wqkv[(size_t)tid*E];              // w_qkv[:,0]
  if (tid < 24*12*64*8){
    int pos = tid & 7;
    int lane = (tid >> 3) & 63;
    int kt  = (tid >> 9) % 12;
    int nt  = tid / 6144;
    int l15 = lane & 15, l4 = lane >> 4;
    int col = nt*16 + l15;
    int k   = kt*32 + l4*8 + pos;
    wvF[tid] = f2bf(wqkv[(size_t)k*E + 385 + col]);        // wv[k][col]
    woF[tid] = f2bf(wout[(size_t)k*D + col]);              // wout[k][col]
  }
}

// ---------------- kA: REGISTER-RESIDENT q + online softmax + weighted row-sum ----
// (R18-exact) 512 threads = 8 waves; chunk = 64 rows in 2 sub-chunks of 32.
__global__ __launch_bounds__(512)
void kA_fused(const float* __restrict__ H, const float* __restrict__ wq,
              float* __restrict__ partial, float* __restrict__ mArr,
              float* __restrict__ lArr){
  __shared__ float red[8][392];   // 12544 B
  __shared__ float qs[32];
  __shared__ float ws[32];
  __shared__ float scaleS;
  const int ch = blockIdx.x, bp = blockIdx.y;
  const int t = threadIdx.x, w = t >> 6, lane = t & 63;
  const size_t base0 = (size_t)bp*NTOK + (size_t)ch*64;

  f32x2 wqr[3];
  #pragma unroll
  for (int seg=0;seg<3;++seg)
    wqr[seg] = *reinterpret_cast<const f32x2*>(wq + lane*2 + seg*128);

  float acc6[6] = {0.f,0.f,0.f,0.f,0.f,0.f};
  float mRun = -3.4e38f, lRun = 0.f;          // meaningful in wave 0 only

  #pragma unroll 1
  for (int s=0; s<2; ++s){
    f32x2 h[4][3];
    #pragma unroll
    for (int j=0;j<4;++j){
      const float* hr = H + (base0 + (size_t)(s*32 + w*4 + j))*D + lane*2;
      #pragma unroll
      for (int seg=0;seg<3;++seg)
        h[j][seg] = *reinterpret_cast<const f32x2*>(hr + seg*128);
    }
    float a[4];
    #pragma unroll
    for (int j=0;j<4;++j)
      a[j] = h[j][0].x*wqr[0].x + h[j][0].y*wqr[0].y
           + h[j][1].x*wqr[1].x + h[j][1].y*wqr[1].y
           + h[j][2].x*wqr[2].x + h[j][2].y*wqr[2].y;
    #pragma unroll
    for (int off=32; off; off>>=1){
      #pragma unroll
      for (int j=0;j<4;++j) a[j] += __shfl_xor(a[j], off, 64);
    }
    if (lane == 0){
      qs[w*4+0]=a[0]; qs[w*4+1]=a[1]; qs[w*4+2]=a[2]; qs[w*4+3]=a[3];
    }
    __syncthreads();

    if (w == 0){
      float q = (lane < 32) ? qs[lane] : -3.4e38f;
      float msub = q;
      #pragma unroll
      for (int off=32; off; off>>=1) msub = fmaxf(msub, __shfl_xor(msub, off, 64));
      float mNew = fmaxf(mRun, msub);
      float sc   = __expf(mRun - mNew);       // s=0: exp(-inf)=0
      float e    = (lane < 32) ? __expf(q - mNew) : 0.f;
      if (lane < 32) ws[lane] = e;
      float lsub = e;
      #pragma unroll
      for (int off=32; off; off>>=1) lsub += __shfl_xor(lsub, off, 64);
      lRun = lRun*sc + lsub;
      mRun = mNew;
      if (lane == 0) scaleS = sc;
    }
    __syncthreads();

    float sc  = scaleS;
    float wj0 = ws[w*4+0], wj1 = ws[w*4+1], wj2 = ws[w*4+2], wj3 = ws[w*4+3];
    #pragma unroll
    for (int seg=0;seg<3;++seg){
      acc6[seg*2]   = acc6[seg*2]*sc
                    + wj0*h[0][seg].x + wj1*h[1][seg].x
                    + wj2*h[2][seg].x + wj3*h[3][seg].x;
      acc6[seg*2+1] = acc6[seg*2+1]*sc
                    + wj0*h[0][seg].y + wj1*h[1][seg].y
                    + wj2*h[2][seg].y + wj3*h[3][seg].y;
    }
  }

  #pragma unroll
  for (int seg=0;seg<3;++seg){
    red[w][lane*2+seg*128]   = acc6[seg*2];
    red[w][lane*2+seg*128+1] = acc6[seg*2+1];
  }
  __syncthreads();
  if (t < D){
    float s8 = 0.f;
    #pragma unroll
    for (int w8=0;w8<8;++w8) s8 += red[w8][t];
    partial[((size_t)bp*NCH + ch)*D + t] = s8;
  }
  if (t == 0){ mArr[bp*NCH + ch] = mRun; lArr[bp*NCH + ch] = lRun; }
}

// ---------------- kB: combine chunks -> cv[bp][j] ----------------
__global__ void kB_cv(const float* __restrict__ partial, const float* __restrict__ mArr,
                      const float* __restrict__ lArr, const float* __restrict__ wqkv,
                      const float* __restrict__ bqkv, float* __restrict__ cv){
  __shared__ float S[D];
  const int bp = blockIdx.x, t = threadIdx.x;   // 384 threads
  float M = -3.4e38f;
  #pragma unroll 4
  for (int c = 0; c < NCH; ++c) M = fmaxf(M, mArr[bp*NCH + c]);
  float num = 0.f, den = 0.f;
  #pragma unroll 2
  for (int c = 0; c < NCH; ++c){
    float f = __expf(mArr[bp*NCH + c] - M);
    num += f * partial[((size_t)bp*NCH + c)*D + t];
    den += f * lArr[bp*NCH + c];
  }
  S[t] = num / den;
  __syncthreads();
  float acc = bqkv[1 + t];
  #pragma unroll 4
  for (int k = 0; k < D; ++k)
    acc += S[k] * wqkv[(size_t)k*E + 1 + t];
  cv[(size_t)bp*D + t] = acc;
}

// ---------------- K5: NT=2 tile pipeline. Tile-1 loads issued during tile-0's
// compute (T14 issue-early/write-late); single LDS buffer; block count halved
// (1024) -> weight L2 volume halved again. R17 body otherwise.
// NOTE: never cap regs via launch_bounds arg2 below need (R9: spill disaster);
// (512,2) allows 128 VGPR, expected use ~112.
#define BM 64
#define LOADW(W, kt, n) (*reinterpret_cast<const s16x8*>(&(W)[((size_t)((n)*12+(kt))*64 + lane)*8]))

__global__ __launch_bounds__(512, 2)
void k5_main(const float* __restrict__ H, const unsigned short* __restrict__ wvF,
             const unsigned short* __restrict__ woF, const float* __restrict__ cv,
             const float* __restrict__ bqkv, const float* __restrict__ bout,
             float* __restrict__ out){
  __shared__ unsigned short As[BM*D];    // 49152 B; A-tile, then R-tile (in place)
  const int bp = blockIdx.y;
  const int g0 = blockIdx.x*2;                 // first of this block's 2 tiles
  const int t = threadIdx.x;
  const int wave = t>>6, lane = t&63;
  const int l15 = lane&15, l4 = lane>>4;
  const int n0 = wave*48;
  const unsigned short* wvW = wvF + (size_t)wave*3*12*512;
  const unsigned short* woW = woF + (size_t)wave*3*12*512;

  // per-thread fragment-order staging offsets (static-indexed array)
  int offs[12];
  #pragma unroll
  for (int i=0;i<12;++i){
    int c = t + i*512;
    int idx8 = c >> 1;
    int l15v = idx8 & 15;
    int l4v  = (idx8 >> 4) & 3;
    int ktv  = (idx8 >> 6) % 12;
    int mv   = idx8 / 768;
    offs[i] = (mv*16 + l15v)*D + ktv*32 + l4v*8 + (c&1)*4;
  }

  const size_t rowbase0 = (size_t)bp*NTOK + (size_t)g0*BM;
  const float* A0 = H + rowbase0*D;
  const float* A1 = A0 + (size_t)BM*D;

  // prologue: load tile 0
  f32x4 inflA[12];
  #pragma unroll
  for (int i=0;i<12;++i)
    inflA[i] = *reinterpret_cast<const f32x4*>(A0 + offs[i]);

  float bv[3], cvv[3];
  s16x8 b0[3], b1[3];
  f32x4 acc[4][3];
  f32x4 inflB[12];

  // ================= TILE 0 =================
  #pragma unroll
  for (int i=0;i<12;++i){
    int c = t + i*512;
    ushort4 b;
    b.x=f2bf(inflA[i].x); b.y=f2bf(inflA[i].y); b.z=f2bf(inflA[i].z); b.w=f2bf(inflA[i].w);
    *reinterpret_cast<ushort4*>(&As[c*4]) = b;
  }
  // issue tile-1 loads — latency hides under the whole tile-0 body
  #pragma unroll
  for (int i=0;i<12;++i)
    inflB[i] = *reinterpret_cast<const f32x4*>(A1 + offs[i]);
  // GEMM1 b-prefetch
  #pragma unroll
  for (int n=0;n<3;++n) b0[n] = LOADW(wvW, 0, n);
  #pragma unroll
  for (int n=0;n<3;++n) b1[n] = LOADW(wvW, 1, n);
  __syncthreads();

  #pragma unroll
  for (int m=0;m<4;++m)
    #pragma unroll
    for (int n=0;n<3;++n)
      acc[m][n] = (f32x4){0.f,0.f,0.f,0.f};
  #pragma unroll
  for (int kt=0; kt<12; ++kt){
    s16x8 bp_[3];
    if (kt < 10){
      #pragma unroll
      for (int n=0;n<3;++n) bp_[n] = LOADW(wvW, kt+2, n);
    }
    s16x8 a[4];
    #pragma unroll
    for (int m=0;m<4;++m)
      a[m] = *reinterpret_cast<const s16x8*>(&As[((m*12+kt)*64 + lane)*8]);
    #pragma unroll
    for (int m=0;m<4;++m)
      #pragma unroll
      for (int n=0;n<3;++n)
        acc[m][n] = __builtin_amdgcn_mfma_f32_16x16x32_bf16(a[m], b0[n], acc[m][n], 0,0,0);
    #pragma unroll
    for (int n=0;n<3;++n){ b0[n] = b1[n]; b1[n] = bp_[n]; }
  }
  // ep1 constants + GEMM2 b-prefetch before barrier
  #pragma unroll
  for (int n=0;n<3;++n){
    int col = n0 + n*16 + l15;
    bv[n]  = bqkv[385+col];
    cvv[n] = cv[(size_t)bp*D + col];
  }
  #pragma unroll
  for (int n=0;n<3;++n) b0[n] = LOADW(woW, 0, n);
  #pragma unroll
  for (int n=0;n<3;++n) b1[n] = LOADW(woW, 1, n);
  __syncthreads();

  #pragma unroll
  for (int n=0;n<3;++n){
    int col  = n0 + n*16 + l15;
    int kt2  = col >> 5;
    int l42  = (col >> 3) & 3;
    int pos2 = col & 7;
    #pragma unroll
    for (int m=0;m<4;++m){
      #pragma unroll
      for (int r=0;r<4;++r){
        int row = l4*4 + r;
        float v = acc[m][n][r] + bv[n];
        v = v > 0.f ? v*cvv[n] : 0.f;
        As[((m*12+kt2)*64 + l42*16 + row)*8 + pos2] = f2bf(v);
      }
    }
  }
  #pragma unroll
  for (int m=0;m<4;++m)
    #pragma unroll
    for (int n=0;n<3;++n)
      acc[m][n] = (f32x4){0.f,0.f,0.f,0.f};
  __syncthreads();

  #pragma unroll
  for (int kt=0; kt<12; ++kt){
    s16x8 bp_[3];
    if (kt < 10){
      #pragma unroll
      for (int n=0;n<3;++n) bp_[n] = LOADW(woW, kt+2, n);
    }
    s16x8 a[4];
    #pragma unroll
    for (int m=0;m<4;++m)
      a[m] = *reinterpret_cast<const s16x8*>(&As[((m*12+kt)*64 + lane)*8]);
    #pragma unroll
    for (int m=0;m<4;++m)
      #pragma unroll
      for (int n=0;n<3;++n)
        acc[m][n] = __builtin_amdgcn_mfma_f32_16x16x32_bf16(a[m], b0[n], acc[m][n], 0,0,0);
    #pragma unroll
    for (int n=0;n<3;++n){ b0[n] = b1[n]; b1[n] = bp_[n]; }
  }
  #pragma unroll
  for (int n=0;n<3;++n){
    int col = n0 + n*16 + l15;
    float bo = bout[col];
    #pragma unroll
    for (int m=0;m<4;++m)
      #pragma unroll
      for (int r=0;r<4;++r){
        int row = m*16 + l4*4 + r;
        out[(rowbase0+row)*D + col] = acc[m][n][r] + bo;
      }
  }

  // ================= TILE 1 =================
  __syncthreads();                       // all GEMM2 As reads done
  #pragma unroll
  for (int i=0;i<12;++i){
    int c = t + i*512;
    ushort4 b;
    b.x=f2bf(inflB[i].x); b.y=f2bf(inflB[i].y); b.z=f2bf(inflB[i].z); b.w=f2bf(inflB[i].w);
    *reinterpret_cast<ushort4*>(&As[c*4]) = b;
  }
  #pragma unroll
  for (int n=0;n<3;++n) b0[n] = LOADW(wvW, 0, n);
  #pragma unroll
  for (int n=0;n<3;++n) b1[n] = LOADW(wvW, 1, n);
  __syncthreads();

  #pragma unroll
  for (int m=0;m<4;++m)
    #pragma unroll
    for (int n=0;n<3;++n)
      acc[m][n] = (f32x4){0.f,0.f,0.f,0.f};
  #pragma unroll
  for (int kt=0; kt<12; ++kt){
    s16x8 bp_[3];
    if (kt < 10){
      #pragma unroll
      for (int n=0;n<3;++n) bp_[n] = LOADW(wvW, kt+2, n);
    }
    s16x8 a[4];
    #pragma unroll
    for (int m=0;m<4;++m)
      a[m] = *reinterpret_cast<const s16x8*>(&As[((m*12+kt)*64 + lane)*8]);
    #pragma unroll
    for (int m=0;m<4;++m)
      #pragma unroll
      for (int n=0;n<3;++n)
        acc[m][n] = __builtin_amdgcn_mfma_f32_16x16x32_bf16(a[m], b0[n], acc[m][n], 0,0,0);
    #pragma unroll
    for (int n=0;n<3;++n){ b0[n] = b1[n]; b1[n] = bp_[n]; }
  }
  #pragma unroll
  for (int n=0;n<3;++n) b0[n] = LOADW(woW, 0, n);
  #pragma unroll
  for (int n=0;n<3;++n) b1[n] = LOADW(woW, 1, n);
  __syncthreads();

  #pragma unroll
  for (int n=0;n<3;++n){
    int col  = n0 + n*16 + l15;
    int kt2  = col >> 5;
    int l42  = (col >> 3) & 3;
    int pos2 = col & 7;
    #pragma unroll
    for (int m=0;m<4;++m){
      #pragma unroll
      for (int r=0;r<4;++r){
        int row = l4*4 + r;
        float v = acc[m][n][r] + bv[n];
        v = v > 0.f ? v*cvv[n] : 0.f;
        As[((m*12+kt2)*64 + l42*16 + row)*8 + pos2] = f2bf(v);
      }
    }
  }
  #pragma unroll
  for (int m=0;m<4;++m)
    #pragma unroll
    for (int n=0;n<3;++n)
      acc[m][n] = (f32x4){0.f,0.f,0.f,0.f};
  __syncthreads();

  #pragma unroll
  for (int kt=0; kt<12; ++kt){
    s16x8 bp_[3];
    if (kt < 10){
      #pragma unroll
      for (int n=0;n<3;++n) bp_[n] = LOADW(woW, kt+2, n);
    }
    s16x8 a[4];
    #pragma unroll
    for (int m=0;m<4;++m)
      a[m] = *reinterpret_cast<const s16x8*>(&As[((m*12+kt)*64 + lane)*8]);
    #pragma unroll
    for (int m=0;m<4;++m)
      #pragma unroll
      for (int n=0;n<3;++n)
        acc[m][n] = __builtin_amdgcn_mfma_f32_16x16x32_bf16(a[m], b0[n], acc[m][n], 0,0,0);
    #pragma unroll
    for (int n=0;n<3;++n){ b0[n] = b1[n]; b1[n] = bp_[n]; }
  }
  {
    const size_t rowbase1 = rowbase0 + BM;
    #pragma unroll
    for (int n=0;n<3;++n){
      int col = n0 + n*16 + l15;
      float bo = bout[col];
      #pragma unroll
      for (int m=0;m<4;++m)
        #pragma unroll
        for (int r=0;r<4;++r){
          int row = m*16 + l4*4 + r;
          out[(rowbase1+row)*D + col] = acc[m][n][r] + bo;
        }
    }
  }
}

extern "C" void kernel_launch(void* const* d_in, const int* in_sizes, int n_in,
                              void* d_out, int out_size, void* d_ws, size_t ws_size,
                              hipStream_t stream){
  const float* H    = (const float*)d_in[0];
  const float* wqkv = (const float*)d_in[1];
  const float* bqkv = (const float*)d_in[2];
  const float* wout = (const float*)d_in[3];
  const float* bout = (const float*)d_in[4];
  float* out = (float*)d_out;

  char* ws = (char*)d_ws;                              // total usage: 3.63 MB
  float*          partial = (float*)(ws + 0x000000);   // 3.0 MB
  float*          mArr    = (float*)(ws + 0x300000);   // 8 KB
  float*          lArr    = (float*)(ws + 0x302000);   // 8 KB
  float*          cv      = (float*)(ws + 0x304000);   // 48 KB
  float*          wq      = (float*)(ws + 0x310000);   // 1.5 KB
  unsigned short* wvF     = (unsigned short*)(ws + 0x311000);  // 288 KB
  unsigned short* woF     = (unsigned short*)(ws + 0x359000);  // 288 KB

  hipLaunchKernelGGL(k0_prep,  dim3(576),              dim3(256), 0, stream, wqkv, wout, wq, wvF, woF);
  hipLaunchKernelGGL(kA_fused, dim3(NCH, BPN),         dim3(512), 0, stream, H, wq, partial, mArr, lArr);
  hipLaunchKernelGGL(kB_cv,    dim3(BPN),              dim3(384), 0, stream, partial, mArr, lArr, wqkv, bqkv, cv);
  hipLaunchKernelGGL(k5_main,  dim3(NTOK/(BM*2), BPN), dim3(512), 0, stream, H, wvF, woF, cv, bqkv, bout, out);
}

// Round 20
// 220.421 us; speedup vs baseline: 1.1270x; 1.1270x over previous
//
#include <hip/hip_runtime.h>

#define D     384
#define E     769      // 1 + 2*D
#define NTOK  4096
#define BPN   32       // B*P
#define NCH   64       // chunks of 64 rows per (b,p)

typedef short s16x8 __attribute__((ext_vector_type(8)));
typedef float f32x4 __attribute__((ext_vector_type(4)));
typedef float f32x2 __attribute__((ext_vector_type(2)));

__device__ __forceinline__ unsigned short f2bf(float f){
  unsigned int u = __builtin_bit_cast(unsigned int, f);
  u += 0x7FFFu + ((u >> 16) & 1u);          // round-to-nearest-even
  return (unsigned short)(u >> 16);
}

// ---------------- K0: pack wq; build FRAGMENT-ORDERED bf16 weights ----------------
__global__ void k0_prep(const float* __restrict__ wqkv, const float* __restrict__ wout,
                        float* __restrict__ wq, unsigned short* __restrict__ wvF,
                        unsigned short* __restrict__ woF){
  int tid = blockIdx.x*256 + threadIdx.x;     // 0 .. 147455
  if (tid < D) wq[tid] = wqkv[(size_t)tid*E];              // w_qkv[:,0]
  if (tid < 24*12*64*8){
    int pos = tid & 7;
    int lane = (tid >> 3) & 63;
    int kt  = (tid >> 9) % 12;
    int nt  = tid / 6144;
    int l15 = lane & 15, l4 = lane >> 4;
    int col = nt*16 + l15;
    int k   = kt*32 + l4*8 + pos;
    wvF[tid] = f2bf(wqkv[(size_t)k*E + 385 + col]);        // wv[k][col]
    woF[tid] = f2bf(wout[(size_t)k*D + col]);              // wout[k][col]
  }
}

// ---------------- kA: REGISTER-RESIDENT q + online softmax + weighted row-sum ----
// (R18-exact) 512 threads = 8 waves; chunk = 64 rows in 2 sub-chunks of 32.
__global__ __launch_bounds__(512)
void kA_fused(const float* __restrict__ H, const float* __restrict__ wq,
              float* __restrict__ partial, float* __restrict__ mArr,
              float* __restrict__ lArr){
  __shared__ float red[8][392];   // 12544 B
  __shared__ float qs[32];
  __shared__ float ws[32];
  __shared__ float scaleS;
  const int ch = blockIdx.x, bp = blockIdx.y;
  const int t = threadIdx.x, w = t >> 6, lane = t & 63;
  const size_t base0 = (size_t)bp*NTOK + (size_t)ch*64;

  f32x2 wqr[3];
  #pragma unroll
  for (int seg=0;seg<3;++seg)
    wqr[seg] = *reinterpret_cast<const f32x2*>(wq + lane*2 + seg*128);

  float acc6[6] = {0.f,0.f,0.f,0.f,0.f,0.f};
  float mRun = -3.4e38f, lRun = 0.f;          // meaningful in wave 0 only

  #pragma unroll 1
  for (int s=0; s<2; ++s){
    f32x2 h[4][3];
    #pragma unroll
    for (int j=0;j<4;++j){
      const float* hr = H + (base0 + (size_t)(s*32 + w*4 + j))*D + lane*2;
      #pragma unroll
      for (int seg=0;seg<3;++seg)
        h[j][seg] = *reinterpret_cast<const f32x2*>(hr + seg*128);
    }
    float a[4];
    #pragma unroll
    for (int j=0;j<4;++j)
      a[j] = h[j][0].x*wqr[0].x + h[j][0].y*wqr[0].y
           + h[j][1].x*wqr[1].x + h[j][1].y*wqr[1].y
           + h[j][2].x*wqr[2].x + h[j][2].y*wqr[2].y;
    #pragma unroll
    for (int off=32; off; off>>=1){
      #pragma unroll
      for (int j=0;j<4;++j) a[j] += __shfl_xor(a[j], off, 64);
    }
    if (lane == 0){
      qs[w*4+0]=a[0]; qs[w*4+1]=a[1]; qs[w*4+2]=a[2]; qs[w*4+3]=a[3];
    }
    __syncthreads();

    if (w == 0){
      float q = (lane < 32) ? qs[lane] : -3.4e38f;
      float msub = q;
      #pragma unroll
      for (int off=32; off; off>>=1) msub = fmaxf(msub, __shfl_xor(msub, off, 64));
      float mNew = fmaxf(mRun, msub);
      float sc   = __expf(mRun - mNew);       // s=0: exp(-inf)=0
      float e    = (lane < 32) ? __expf(q - mNew) : 0.f;
      if (lane < 32) ws[lane] = e;
      float lsub = e;
      #pragma unroll
      for (int off=32; off; off>>=1) lsub += __shfl_xor(lsub, off, 64);
      lRun = lRun*sc + lsub;
      mRun = mNew;
      if (lane == 0) scaleS = sc;
    }
    __syncthreads();

    float sc  = scaleS;
    float wj0 = ws[w*4+0], wj1 = ws[w*4+1], wj2 = ws[w*4+2], wj3 = ws[w*4+3];
    #pragma unroll
    for (int seg=0;seg<3;++seg){
      acc6[seg*2]   = acc6[seg*2]*sc
                    + wj0*h[0][seg].x + wj1*h[1][seg].x
                    + wj2*h[2][seg].x + wj3*h[3][seg].x;
      acc6[seg*2+1] = acc6[seg*2+1]*sc
                    + wj0*h[0][seg].y + wj1*h[1][seg].y
                    + wj2*h[2][seg].y + wj3*h[3][seg].y;
    }
  }

  #pragma unroll
  for (int seg=0;seg<3;++seg){
    red[w][lane*2+seg*128]   = acc6[seg*2];
    red[w][lane*2+seg*128+1] = acc6[seg*2+1];
  }
  __syncthreads();
  if (t < D){
    float s8 = 0.f;
    #pragma unroll
    for (int w8=0;w8<8;++w8) s8 += red[w8][t];
    partial[((size_t)bp*NCH + ch)*D + t] = s8;
  }
  if (t == 0){ mArr[bp*NCH + ch] = mRun; lArr[bp*NCH + ch] = lRun; }
}

// ---------------- kB: combine chunks -> cv[bp][j] ----------------
__global__ void kB_cv(const float* __restrict__ partial, const float* __restrict__ mArr,
                      const float* __restrict__ lArr, const float* __restrict__ wqkv,
                      const float* __restrict__ bqkv, float* __restrict__ cv){
  __shared__ float S[D];
  const int bp = blockIdx.x, t = threadIdx.x;   // 384 threads
  float M = -3.4e38f;
  #pragma unroll 4
  for (int c = 0; c < NCH; ++c) M = fmaxf(M, mArr[bp*NCH + c]);
  float num = 0.f, den = 0.f;
  #pragma unroll 2
  for (int c = 0; c < NCH; ++c){
    float f = __expf(mArr[bp*NCH + c] - M);
    num += f * partial[((size_t)bp*NCH + c)*D + t];
    den += f * lArr[bp*NCH + c];
  }
  S[t] = num / den;
  __syncthreads();
  float acc = bqkv[1 + t];
  #pragma unroll 4
  for (int k = 0; k < D; ++k)
    acc += S[k] * wqkv[(size_t)k*E + 1 + t];
  cv[(size_t)bp*D + t] = acc;
}

// ---------------- K5: one-pass BM=64, 8 waves (R17/R18-exact best body) ----------
// wave w owns n-tiles {3w..3w+2}, ALL 4 m-tiles (B read once/block); 2-deep
// named-register B prefetch. VGPR 64 = the 8-waves/SIMD sweet spot — do NOT add
// in-flight state (R19: +44 VGPR -> occupancy halved, -30 us) and never cap
// regs via launch_bounds arg2 (R9: forced 48 VGPR -> GB-scale spill).
#define BM 64
#define LOADW(W, kt, n) (*reinterpret_cast<const s16x8*>(&(W)[((size_t)((n)*12+(kt))*64 + lane)*8]))

__global__ __launch_bounds__(512, 2)
void k5_main(const float* __restrict__ H, const unsigned short* __restrict__ wvF,
             const unsigned short* __restrict__ woF, const float* __restrict__ cv,
             const float* __restrict__ bqkv, const float* __restrict__ bout,
             float* __restrict__ out){
  __shared__ unsigned short As[BM*D];    // 49152 B; A-tile, then R-tile (in place)
  const int bp = blockIdx.y;
  const int m0 = blockIdx.x*BM;
  const size_t rowbase = (size_t)bp*NTOK + m0;
  const float* A = H + rowbase*D;
  const int t = threadIdx.x;
  const int wave = t>>6, lane = t&63;
  const int l15 = lane&15, l4 = lane>>4;
  const int n0 = wave*48;                      // wave owns 48 output cols (3 n-tiles)
  const unsigned short* wvW = wvF + (size_t)wave*3*12*512;
  const unsigned short* woW = woF + (size_t)wave*3*12*512;

  // stage 64 H rows (fp32, plain, coalesced) -> bf16 LDS in FRAGMENT order
  #pragma unroll
  for (int i=0;i<12;++i){
    int c = t + i*512;                   // 0..6143 (float4 chunks)
    int idx8 = c >> 1;
    int l15v = idx8 & 15;
    int l4v  = (idx8 >> 4) & 3;
    int ktv  = (idx8 >> 6) % 12;
    int mv   = idx8 / 768;
    f32x4 v = *reinterpret_cast<const f32x4*>(
        A + (size_t)(mv*16 + l15v)*D + ktv*32 + l4v*8 + (c&1)*4);
    ushort4 b;
    b.x=f2bf(v.x); b.y=f2bf(v.y); b.z=f2bf(v.z); b.w=f2bf(v.w);
    *reinterpret_cast<ushort4*>(&As[c*4]) = b;
  }

  // issue GEMM1's first two kts' weight loads BEFORE the barrier
  s16x8 b0[3], b1[3];
  #pragma unroll
  for (int n=0;n<3;++n) b0[n] = LOADW(wvW, 0, n);
  #pragma unroll
  for (int n=0;n<3;++n) b1[n] = LOADW(wvW, 1, n);
  __syncthreads();

  f32x4 acc[4][3] = {};
  // GEMM1: v = A @ wv — 2-deep B prefetch, fully unrolled (static indexing)
  #pragma unroll
  for (int kt=0; kt<12; ++kt){
    s16x8 bp_[3];
    if (kt < 10){
      #pragma unroll
      for (int n=0;n<3;++n) bp_[n] = LOADW(wvW, kt+2, n);
    }
    s16x8 a[4];
    #pragma unroll
    for (int m=0;m<4;++m)
      a[m] = *reinterpret_cast<const s16x8*>(&As[((m*12+kt)*64 + lane)*8]);
    #pragma unroll
    for (int m=0;m<4;++m)
      #pragma unroll
      for (int n=0;n<3;++n)
        acc[m][n] = __builtin_amdgcn_mfma_f32_16x16x32_bf16(a[m], b0[n], acc[m][n], 0,0,0);
    #pragma unroll
    for (int n=0;n<3;++n){ b0[n] = b1[n]; b1[n] = bp_[n]; }
  }

  // issue ep1 constants AND GEMM2's first two kts' weight loads BEFORE the barrier
  float bv[3], cvv[3];
  #pragma unroll
  for (int n=0;n<3;++n){
    int col = n0 + n*16 + l15;
    bv[n]  = bqkv[385+col];
    cvv[n] = cv[(size_t)bp*D + col];
  }
  #pragma unroll
  for (int n=0;n<3;++n) b0[n] = LOADW(woW, 0, n);
  #pragma unroll
  for (int n=0;n<3;++n) b1[n] = LOADW(woW, 1, n);
  __syncthreads();   // everyone done reading As before overwrite

  // epilogue1: r = relu(v + bv) * cv  -> bf16 back into As in FRAGMENT order
  #pragma unroll
  for (int n=0;n<3;++n){
    int col  = n0 + n*16 + l15;
    int kt2  = col >> 5;
    int l42  = (col >> 3) & 3;
    int pos2 = col & 7;
    #pragma unroll
    for (int m=0;m<4;++m){
      #pragma unroll
      for (int r=0;r<4;++r){
        int row = l4*4 + r;
        float v = acc[m][n][r] + bv[n];
        v = v > 0.f ? v*cvv[n] : 0.f;
        As[((m*12+kt2)*64 + l42*16 + row)*8 + pos2] = f2bf(v);
      }
    }
  }
  #pragma unroll
  for (int m=0;m<4;++m)
    #pragma unroll
    for (int n=0;n<3;++n)
      acc[m][n] = (f32x4){0.f,0.f,0.f,0.f};
  __syncthreads();

  // GEMM2: out = R @ Wout — same 2-deep B prefetch (b0/b1 already resolved)
  #pragma unroll
  for (int kt=0; kt<12; ++kt){
    s16x8 bp_[3];
    if (kt < 10){
      #pragma unroll
      for (int n=0;n<3;++n) bp_[n] = LOADW(woW, kt+2, n);
    }
    s16x8 a[4];
    #pragma unroll
    for (int m=0;m<4;++m)
      a[m] = *reinterpret_cast<const s16x8*>(&As[((m*12+kt)*64 + lane)*8]);
    #pragma unroll
    for (int m=0;m<4;++m)
      #pragma unroll
      for (int n=0;n<3;++n)
        acc[m][n] = __builtin_amdgcn_mfma_f32_16x16x32_bf16(a[m], b0[n], acc[m][n], 0,0,0);
    #pragma unroll
    for (int n=0;n<3;++n){ b0[n] = b1[n]; b1[n] = bp_[n]; }
  }

  // direct stores (R2-proven path)
  #pragma unroll
  for (int n=0;n<3;++n){
    int col = n0 + n*16 + l15;
    float bo = bout[col];
    #pragma unroll
    for (int m=0;m<4;++m)
      #pragma unroll
      for (int r=0;r<4;++r){
        int row = m*16 + l4*4 + r;
        out[(rowbase+row)*D + col] = acc[m][n][r] + bo;
      }
  }
}

extern "C" void kernel_launch(void* const* d_in, const int* in_sizes, int n_in,
                              void* d_out, int out_size, void* d_ws, size_t ws_size,
                              hipStream_t stream){
  const float* H    = (const float*)d_in[0];
  const float* wqkv = (const float*)d_in[1];
  const float* bqkv = (const float*)d_in[2];
  const float* wout = (const float*)d_in[3];
  const float* bout = (const float*)d_in[4];
  float* out = (float*)d_out;

  char* ws = (char*)d_ws;                              // total usage: 3.63 MB (R8-validated)
  float*          partial = (float*)(ws + 0x000000);   // 3.0 MB
  float*          mArr    = (float*)(ws + 0x300000);   // 8 KB
  float*          lArr    = (float*)(ws + 0x302000);   // 8 KB
  float*          cv      = (float*)(ws + 0x304000);   // 48 KB
  float*          wq      = (float*)(ws + 0x310000);   // 1.5 KB
  unsigned short* wvF     = (unsigned short*)(ws + 0x311000);  // 288 KB
  unsigned short* woF     = (unsigned short*)(ws + 0x359000);  // 288 KB

  hipLaunchKernelGGL(k0_prep,  dim3(576),          dim3(256), 0, stream, wqkv, wout, wq, wvF, woF);
  hipLaunchKernelGGL(kA_fused, dim3(NCH, BPN),     dim3(512), 0, stream, H, wq, partial, mArr, lArr);
  hipLaunchKernelGGL(kB_cv,    dim3(BPN),          dim3(384), 0, stream, partial, mArr, lArr, wqkv, bqkv, cv);
  hipLaunchKernelGGL(k5_main,  dim3(NTOK/BM, BPN), dim3(512), 0, stream, H, wvF, woF, cv, bqkv, bout, out);
}